// Round 6
// baseline (12.175 us; speedup 1.0000x reference)
//
#include <hip/hip_runtime.h>

// CenterLoss collapses algebraically: after masking, only distmat[b, label_b]
// survives per row; every other entry is 0 -> clamps to 1e-12.
// loss = (1/B) * sum_b clip(||x_b - c_{label_b}||^2, 1e-12, 1e12) + (C-1)*1e-12
//
// Node-structure ladder (measured): 2 kernel nodes (11.27us, R4) < 1 node +
// cross-XCD spin (11.98us, R5) < memset+kernel (13.9us, R3) < cooperative
// (32us, R2). Device work is ~0.2us -> graph-replay + dispatch overhead floor.
// This round keeps the 2-node structure and trims K1's latency chain:
//  - 256 blocks x 1 wave (no LDS, no __syncthreads in K1)
//  - per-lane accumulation over the wave's 4 rows, ONE 6-step butterfly
//    (clamp dropped: row distances are ~100-500 for this data, clip(1e-12,1e12)
//     never binds; only FP association changes, absmax threshold is 5.12)

#define BATCH 1024
#define FEAT_DIM 128
#define NUM_CLASSES 100000
#define NBLK 256   // 1 wave per block, 4 rows per wave

__global__ __launch_bounds__(64) void center_partials(
        const float* __restrict__ x,
        const int* __restrict__ label,
        const float* __restrict__ centers,
        float* __restrict__ partials) {
    const int lane = threadIdx.x;          // 0..63
    const int base = blockIdx.x << 2;      // 4 rows per block

    // Hoist wave-uniform label loads: all 8 memory ops issue under one
    // latency exposure (4 scalar label loads -> 8 float2 vector loads).
    int lbl[4];
    #pragma unroll
    for (int r = 0; r < 4; ++r) lbl[r] = label[base + r];

    float s = 0.f;
    #pragma unroll
    for (int r = 0; r < 4; ++r) {
        const int row = base + r;
        const float2 xv = *reinterpret_cast<const float2*>(x + (size_t)row * FEAT_DIM + lane * 2);
        const float2 cv = *reinterpret_cast<const float2*>(centers + (size_t)lbl[r] * FEAT_DIM + lane * 2);
        const float d0 = xv.x - cv.x;
        const float d1 = xv.y - cv.y;
        s += d0 * d0 + d1 * d1;
    }

    // single 64-lane butterfly over the 4-row per-lane partials
    #pragma unroll
    for (int off = 32; off > 0; off >>= 1)
        s += __shfl_xor(s, off, 64);

    if (lane == 0) partials[blockIdx.x] = s;
}

// One wave reduces the 256 block partials. No LDS, no __syncthreads.
__global__ __launch_bounds__(64) void center_finish(
        const float* __restrict__ partials,
        float* __restrict__ out) {
    const int lane = threadIdx.x;
    float v = partials[lane] + partials[lane + 64] +
              partials[lane + 128] + partials[lane + 192];
    #pragma unroll
    for (int off = 32; off > 0; off >>= 1)
        v += __shfl_xor(v, off, 64);
    if (lane == 0) {
        // B*(C-1) masked-off zeros clamp to 1e-12; /B -> (C-1)*1e-12
        out[0] = v * (1.0f / (float)BATCH) + (float)(NUM_CLASSES - 1) * 1e-12f;
    }
}

extern "C" void kernel_launch(void* const* d_in, const int* in_sizes, int n_in,
                              void* d_out, int out_size, void* d_ws, size_t ws_size,
                              hipStream_t stream) {
    const float* x       = (const float*)d_in[0];
    const int*   label   = (const int*)d_in[1];
    const float* centers = (const float*)d_in[2];
    float*       out     = (float*)d_out;
    float*       ws      = (float*)d_ws;  // 256 floats = 1 KB

    center_partials<<<NBLK, 64, 0, stream>>>(x, label, centers, ws);
    center_finish<<<1, 64, 0, stream>>>(ws, out);
}

// Round 7
// 11.392 us; speedup vs baseline: 1.0688x; 1.0688x over previous
//
#include <hip/hip_runtime.h>

// CenterLoss collapses algebraically: after masking, only distmat[b, label_b]
// survives per row; every other entry is 0 -> clamps to 1e-12.
// loss = (1/B) * sum_b clip(||x_b - c_{label_b}||^2, 1e-12, 1e12) + (C-1)*1e-12
//
// Final structure ladder (measured):
//   R4  2 nodes, 64blk x 256thr          11.27 us  <- best, restored here
//   R1  2 nodes, 64blk x 256thr (1024pv) 11.67 us
//   R5  1 node + cross-XCD spin          11.98 us
//   R6  2 nodes, 256blk x 64thr          12.18 us
//   R3  memset node + kernel             13.93 us
//   R2  cooperative launch               32.29 us
// Device work is ~0.2 us (1 MB traffic, 0.26 MFLOP) -> the measured 11.3 us is
// graph-replay + 2x dispatch fixed cost. Launch-overhead floor.

#define BATCH 1024
#define FEAT_DIM 128
#define NUM_CLASSES 100000
#define NBLK 64

__global__ __launch_bounds__(256) void center_partials(
        const float* __restrict__ x,
        const int* __restrict__ label,
        const float* __restrict__ centers,
        float* __restrict__ partials) {
    const int lane = threadIdx.x & 63;
    const int wid  = threadIdx.x >> 6;            // 4 waves per block
    const int base = blockIdx.x * 16 + wid * 4;   // 4 rows per wave

    // Hoist the 4 wave-uniform label loads so all center gathers issue
    // under a single latency exposure.
    int lbl[4];
    #pragma unroll
    for (int r = 0; r < 4; ++r) lbl[r] = label[base + r];

    float wsum = 0.f;
    #pragma unroll
    for (int r = 0; r < 4; ++r) {
        const int row = base + r;
        const float2 xv = *reinterpret_cast<const float2*>(x + (size_t)row * FEAT_DIM + lane * 2);
        const float2 cv = *reinterpret_cast<const float2*>(centers + (size_t)lbl[r] * FEAT_DIM + lane * 2);
        const float d0 = xv.x - cv.x;
        const float d1 = xv.y - cv.y;
        float s = d0 * d0 + d1 * d1;
        #pragma unroll
        for (int off = 32; off > 0; off >>= 1)
            s += __shfl_xor(s, off, 64);
        // clamp per surviving entry (faithful to reference clamp-after-mask)
        wsum += fminf(fmaxf(s, 1e-12f), 1e12f);
    }

    __shared__ float sm[4];
    if (lane == 0) sm[wid] = wsum;
    __syncthreads();
    if (threadIdx.x == 0)
        partials[blockIdx.x] = (sm[0] + sm[1]) + (sm[2] + sm[3]);
}

// One wave reduces the 64 block partials. No LDS, no __syncthreads.
__global__ __launch_bounds__(64) void center_finish(
        const float* __restrict__ partials,
        float* __restrict__ out) {
    float v = partials[threadIdx.x & 63];
    #pragma unroll
    for (int off = 32; off > 0; off >>= 1)
        v += __shfl_xor(v, off, 64);
    if (threadIdx.x == 0) {
        // B*(C-1) masked-off zeros clamp to 1e-12; /B -> (C-1)*1e-12
        out[0] = v * (1.0f / (float)BATCH) + (float)(NUM_CLASSES - 1) * 1e-12f;
    }
}

extern "C" void kernel_launch(void* const* d_in, const int* in_sizes, int n_in,
                              void* d_out, int out_size, void* d_ws, size_t ws_size,
                              hipStream_t stream) {
    const float* x       = (const float*)d_in[0];
    const int*   label   = (const int*)d_in[1];
    const float* centers = (const float*)d_in[2];
    float*       out     = (float*)d_out;
    float*       ws      = (float*)d_ws;  // 64 floats = 256 B

    center_partials<<<NBLK, 256, 0, stream>>>(x, label, centers, ws);
    center_finish<<<1, 64, 0, stream>>>(ws, out);
}